// Round 10
// baseline (369.508 us; speedup 1.0000x reference)
//
#include <hip/hip_runtime.h>
#include <hip/hip_bf16.h>
#include <cstdint>

// ---------------------------------------------------------------------------
// InteractionMHA, fp32 I/O, bf16-MFMA compute.
// Per branch:
//   Q  = rep_q  @ Wq^T + bq           (gemm_kernel -> BQ bf16)   11us, roofline
//   K  = rep_kv @ Wk^T + bk           (gemm_kernel -> BK bf16)   11us, roofline
//   Vt = Wv @ rep_kv^T (+bv per row)  (gemm_kernel swapped -> BV)11us, roofline
//   out = gelu(softmax(QK^T/16)V @ Wm^T + bm)  (attn_out_kernel, fused, fp32)
//
// Round-10: projections reverted to r7's separate 128^2 gemms (the only
// structure measured AT the HBM roofline; fused qkv variants r8/r9 were
// 1.2-2x slower). attn+out-proj fusion retried with __launch_bounds__(512,2):
// r6's 129us failure was VGPR=64 strangulation from (512,4) (xacc+oacc are
// 64 regs each); phase-disjoint peak ~110 fits the 128 cap spill-free.
// ---------------------------------------------------------------------------

typedef short s16x8 __attribute__((ext_vector_type(8)));
typedef float f32x4 __attribute__((ext_vector_type(4)));

__device__ __forceinline__ s16x8 cvt8(const float* p) {
  float4 a0 = *(const float4*)p, a1 = *(const float4*)(p + 4);
  union { s16x8 v; __bf16 e[8]; } u;
  u.e[0] = (__bf16)a0.x; u.e[1] = (__bf16)a0.y; u.e[2] = (__bf16)a0.z; u.e[3] = (__bf16)a0.w;
  u.e[4] = (__bf16)a1.x; u.e[5] = (__bf16)a1.y; u.e[6] = (__bf16)a1.z; u.e[7] = (__bf16)a1.w;
  return u.v;
}
__device__ __forceinline__ float fast_gelu(float x) {
  float ax = fabsf(x);
  float t = 1.0f / (1.0f + 0.3275911f * (ax * 0.70710678f));
  float y = t * (0.254829592f + t * (-0.284496736f + t * (1.421413741f +
            t * (-1.453152027f + t * 1.061405429f))));
  float er = 1.0f - y * __expf(-0.5f * ax * ax);
  er = (x < 0.f) ? -er : er;
  return 0.5f * x * (1.0f + er);
}

__global__ void sentinel_kernel(float* out, float v) {
  if (threadIdx.x == 0 && blockIdx.x == 0) out[0] = v;
}

// ---------- parallel offsets scan (B <= 512), dtype self-validating --------
__global__ __launch_bounds__(512) void scan_kernel(
    const int* __restrict__ na, int* __restrict__ offs,
    int B, int total, float* out)
{
  __shared__ int s32[512];
  __shared__ int s64[512];
  const int t = threadIdx.x;
  int v32 = 0, v64 = 0;
  if (t < B) {
    v32 = na[t];
    v64 = (int)((const long long*)na)[t];
  }
  s32[t] = v32; s64[t] = v64;
  __syncthreads();
  for (int o = 1; o < 512; o <<= 1) {
    int a = (t >= o) ? s32[t - o] : 0;
    int b = (t >= o) ? s64[t - o] : 0;
    __syncthreads();
    s32[t] += a; s64[t] += b;
    __syncthreads();
  }
  int tot32 = s32[B - 1], tot64 = s64[B - 1];
  bool ok32 = (tot32 == total), ok64 = (tot64 == total);
  if (t < B) offs[t] = ok32 ? (s32[t] - v32) : ok64 ? (s64[t] - v64) : 0;
  if (t == 0) {
    offs[B] = ok32 ? tot32 : ok64 ? tot64 : 0;
    if (!ok32 && !ok64) out[0] = 31337.0f;
  }
}

// ---------- fp32 -> bf16 weight convert (Wm for fused out-proj) ------------
__global__ __launch_bounds__(256) void cvt_kernel(
    const float* __restrict__ in, __bf16* __restrict__ out) {
  int i = (blockIdx.x * 256 + threadIdx.x) * 4;
  float4 f = *(const float4*)(in + i);
  out[i + 0] = (__bf16)f.x; out[i + 1] = (__bf16)f.y;
  out[i + 2] = (__bf16)f.z; out[i + 3] = (__bf16)f.w;
}

// ---------- GEMM (r7 proven, HBM-roofline): C = A@Bw^T + bias, bf16 out ----
__global__ __launch_bounds__(256) void gemm_kernel(
    const float* __restrict__ A, const float* __restrict__ Bw,
    const float* __restrict__ bias, __bf16* __restrict__ C,
    int N, int biasRow)
{
  __shared__ __bf16 At[128 * 32];
  __shared__ __bf16 Bt[128 * 32];
  const int t = threadIdx.x;
  const int lane = t & 63, w = t >> 6;
  const int wr = w >> 1, wc = w & 1;
  const int l15 = lane & 15, l4 = lane >> 4;
  const int by = blockIdx.x, bx = blockIdx.y;

  f32x4 acc[4][4];
  for (int m = 0; m < 4; ++m)
    for (int nn = 0; nn < 4; ++nn) acc[m][nn] = (f32x4){0.f, 0.f, 0.f, 0.f};

  for (int kk = 0; kk < 256; kk += 32) {
    for (int j = 0; j < 2; ++j) {
      int c = t + j * 256;
      int row = c >> 2, off0 = (c & 3) * 8;
      *(s16x8*)(&At[row * 32 + off0]) = cvt8(A + (size_t)(by * 128 + row) * 256 + kk + off0);
      *(s16x8*)(&Bt[row * 32 + off0]) = cvt8(Bw + (size_t)(bx * 128 + row) * 256 + kk + off0);
    }
    __syncthreads();
    s16x8 af[4], bfr[4];
    for (int m = 0; m < 4; ++m)
      af[m] = *(const s16x8*)(&At[(wr * 64 + m * 16 + l15) * 32 + l4 * 8]);
    for (int nn = 0; nn < 4; ++nn)
      bfr[nn] = *(const s16x8*)(&Bt[(wc * 64 + nn * 16 + l15) * 32 + l4 * 8]);
    for (int m = 0; m < 4; ++m)
      for (int nn = 0; nn < 4; ++nn)
        acc[m][nn] = __builtin_amdgcn_mfma_f32_16x16x32_bf16(af[m], bfr[nn], acc[m][nn], 0, 0, 0);
    __syncthreads();
  }

  for (int m = 0; m < 4; ++m) {
    int row0 = by * 128 + wr * 64 + m * 16 + l4 * 4;
    for (int nn = 0; nn < 4; ++nn) {
      int col = bx * 128 + wc * 64 + nn * 16 + l15;
      float bc = biasRow ? 0.f : bias[col];
      for (int r = 0; r < 4; ++r) {
        int row = row0 + r;
        float v = acc[m][nn][r] + (biasRow ? bias[row] : bc);
        C[(size_t)row * N + col] = (__bf16)v;
      }
    }
  }
}

// ---------- fused attention + out-proj + GELU (fp32 out) -------------------
// 1 block/graph, 8 waves, LDS region reused K -> P -> XT.
//  1) stage K; Q frags     2) S=QK^T        3) softmax -> Plds
//  4) PV (V in-loop, wave w owns d [w*32,+32), all 128 q)
//  5) xacc -> XT[q][d]     6) O = XT@Wm^T (wave w: q [w*16,+16)), gelu, fp32
#define KSTR 264
#define PSTR 136
__global__ __launch_bounds__(512, 2) void attn_out_kernel(
    const __bf16* __restrict__ Q, const __bf16* __restrict__ Km,
    const __bf16* __restrict__ Vt, const __bf16* __restrict__ Wm,
    const float* __restrict__ bm, float* __restrict__ Out,
    const int* __restrict__ offs, int total)
{
  __shared__ __bf16 smem[128 * KSTR];                 // 67.6 KB
  __bf16 (*Klds)[KSTR] = (__bf16(*)[KSTR])smem;
  __bf16 (*Plds)[PSTR] = (__bf16(*)[PSTR])smem;       // alias after QK
  __bf16 (*XT)[KSTR]   = (__bf16(*)[KSTR])smem;       // alias after PV

  const int g = blockIdx.x;
  const int off = offs[g];
  const int n = offs[g + 1] - off;
  const int t = threadIdx.x, lane = t & 63, w = t >> 6;
  const int l15 = lane & 15, l4 = lane >> 4;
  const bool qact = (w * 16) < n;

  // ---- phase 1: stage K rows 0..127 (overrun past n reads valid ws)
  uint4 kst[8];
  #pragma unroll
  for (int j = 0; j < 8; ++j) {
    int row = j * 16 + (t >> 5);
    kst[j] = *(const uint4*)((const char*)(Km + (size_t)(off + row) * 256) + (t & 31) * 16);
  }
  s16x8 qf[8];
  if (qact) {
    int qr = w * 16 + l15; if (qr >= n) qr = n - 1;
    const __bf16* qp = Q + (size_t)(off + qr) * 256 + l4 * 8;
    #pragma unroll
    for (int kk = 0; kk < 8; ++kk) qf[kk] = *(const s16x8*)(qp + kk * 32);
  }
  #pragma unroll
  for (int j = 0; j < 8; ++j) {
    int row = j * 16 + (t >> 5);
    *(uint4*)((char*)&Klds[row][0] + (t & 31) * 16) = kst[j];
  }
  __syncthreads();

  // ---- phase 2: S = Q K^T
  f32x4 sacc[8];
  #pragma unroll
  for (int i = 0; i < 8; ++i) sacc[i] = (f32x4){0.f, 0.f, 0.f, 0.f};
  if (qact) {
    #pragma unroll
    for (int kt = 0; kt < 8; ++kt) {
      if (kt * 16 < n) {
        const __bf16* kp = &Klds[kt * 16 + l15][l4 * 8];
        #pragma unroll
        for (int kk = 0; kk < 8; ++kk) {
          s16x8 kf = *(const s16x8*)(kp + kk * 32);
          sacc[kt] = __builtin_amdgcn_mfma_f32_16x16x32_bf16(qf[kk], kf, sacc[kt], 0, 0, 0);
        }
      }
    }
  }
  __syncthreads();                                    // Klds reads complete

  // ---- phase 3: softmax (regs) -> Plds bf16
  if (qact) {
    #pragma unroll
    for (int r = 0; r < 4; ++r) {
      float sv[8];
      float m = -1e30f;
      #pragma unroll
      for (int kt = 0; kt < 8; ++kt) {
        int key = kt * 16 + l15;
        float v = (key < n) ? sacc[kt][r] * 0.0625f : -1e30f;
        sv[kt] = v; m = fmaxf(m, v);
      }
      for (int o = 1; o < 16; o <<= 1) m = fmaxf(m, __shfl_xor(m, o));
      float p[8], sum = 0.f;
      #pragma unroll
      for (int kt = 0; kt < 8; ++kt) { p[kt] = __expf(sv[kt] - m); sum += p[kt]; }
      for (int o = 1; o < 16; o <<= 1) sum += __shfl_xor(sum, o);
      float inv = 1.f / sum;
      int q = w * 16 + l4 * 4 + r;
      #pragma unroll
      for (int kt = 0; kt < 8; ++kt)
        Plds[q][kt * 16 + l15] = (__bf16)(p[kt] * inv);   // masked keys -> 0
    }
  }
  __syncthreads();                                    // Plds complete

  // ---- phase 4: PV (V in-loop, proven r4 pattern)
  const int dbase = w * 32;
  f32x4 xacc[2][8];
  #pragma unroll
  for (int dt = 0; dt < 2; ++dt)
    #pragma unroll
    for (int qm = 0; qm < 8; ++qm) xacc[dt][qm] = (f32x4){0.f, 0.f, 0.f, 0.f};

  #pragma unroll
  for (int dt = 0; dt < 2; ++dt) {
    int d = dbase + dt * 16 + l15;
    s16x8 vf[4];
    #pragma unroll
    for (int ks = 0; ks < 4; ++ks) {
      int kc = off + ks * 32 + l4 * 8;
      if (kc > total - 8) kc = total - 8;             // P=0 there; data finite
      vf[ks] = *(const s16x8*)(Vt + (size_t)d * total + kc);
    }
    #pragma unroll
    for (int qm = 0; qm < 8; ++qm) {
      #pragma unroll
      for (int ks = 0; ks < 4; ++ks) {
        if (ks * 32 < n) {
          s16x8 pa = *(const s16x8*)(&Plds[qm * 16 + l15][ks * 32 + l4 * 8]);
          xacc[dt][qm] = __builtin_amdgcn_mfma_f32_16x16x32_bf16(pa, vf[ks], xacc[dt][qm], 0, 0, 0);
        }
      }
    }
  }
  __syncthreads();                                    // Plds reads done

  // ---- phase 5: xacc -> XT[q][d]
  #pragma unroll
  for (int dt = 0; dt < 2; ++dt)
    #pragma unroll
    for (int qm = 0; qm < 8; ++qm)
      #pragma unroll
      for (int r = 0; r < 4; ++r)
        XT[qm * 16 + l4 * 4 + r][dbase + dt * 16 + l15] = (__bf16)xacc[dt][qm][r];
  __syncthreads();                                    // XT complete

  // ---- phase 6: O[16 q][256] = XT @ Wm^T (Wm bf16, L2)
  f32x4 oacc[16];
  #pragma unroll
  for (int i = 0; i < 16; ++i) oacc[i] = (f32x4){0.f, 0.f, 0.f, 0.f};
  #pragma unroll
  for (int ks = 0; ks < 8; ++ks) {
    s16x8 af = *(const s16x8*)(&XT[w * 16 + l15][ks * 32 + l4 * 8]);
    const __bf16* wp = Wm + (size_t)l15 * 256 + ks * 32 + l4 * 8;
    #pragma unroll
    for (int jt = 0; jt < 16; ++jt) {
      s16x8 bfr = *(const s16x8*)(wp + (size_t)jt * 16 * 256);
      oacc[jt] = __builtin_amdgcn_mfma_f32_16x16x32_bf16(af, bfr, oacc[jt], 0, 0, 0);
    }
  }

  // epilogue: +bias, gelu, fp32 store (rows q<n)
  #pragma unroll
  for (int jt = 0; jt < 16; ++jt) {
    int col = jt * 16 + l15;
    float bb = bm[col];
    #pragma unroll
    for (int r = 0; r < 4; ++r) {
      int q = w * 16 + l4 * 4 + r;
      if (q < n)
        Out[(size_t)(off + q) * 256 + col] = fast_gelu(oacc[jt][r] + bb);
    }
  }
}

// ---------------------------------------------------------------------------
extern "C" void kernel_launch(void* const* d_in, const int* in_sizes, int n_in,
                              void* d_out, int out_size, void* d_ws, size_t ws_size,
                              hipStream_t stream) {
  const float* rep2d = (const float*)d_in[0];
  const float* rep3d = (const float*)d_in[1];
  const int*   na    = (const int*)d_in[2];
  const float* wq23 = (const float*)d_in[3];  const float* bq23 = (const float*)d_in[4];
  const float* wk23 = (const float*)d_in[5];  const float* bk23 = (const float*)d_in[6];
  const float* wv23 = (const float*)d_in[7];  const float* bv23 = (const float*)d_in[8];
  const float* wq32 = (const float*)d_in[9];  const float* bq32 = (const float*)d_in[10];
  const float* wk32 = (const float*)d_in[11]; const float* bk32 = (const float*)d_in[12];
  const float* wv32 = (const float*)d_in[13]; const float* bv32 = (const float*)d_in[14];
  const float* wm23 = (const float*)d_in[15]; const float* bm23 = (const float*)d_in[16];
  const float* wm32 = (const float*)d_in[17]; const float* bm32 = (const float*)d_in[18];

  const int B = in_sizes[2];
  const int total = in_sizes[0] / 256;           // 40960
  float* out = (float*)d_out;

  char* ws = (char*)d_ws;
  const size_t SZ = (size_t)total * 256 * sizeof(__bf16);  // 20.97 MB
  const size_t WMB = 65536 * sizeof(__bf16);               // 128 KB each
  const size_t need = 8192 + 2 * WMB + 3 * SZ;             // 63.2 MB (proven ok)
  if (ws_size < need) {
    sentinel_kernel<<<1, 64, 0, stream>>>(out, 54321.0f);
    return;
  }
  int*    offs = (int*)ws;
  __bf16* WM0 = (__bf16*)(ws + 8192);
  __bf16* WM1 = (__bf16*)(ws + 8192 + WMB);
  __bf16* BQ  = (__bf16*)(ws + 8192 + 2 * WMB);
  __bf16* BK  = (__bf16*)(ws + 8192 + 2 * WMB + SZ);
  __bf16* BV  = (__bf16*)(ws + 8192 + 2 * WMB + 2 * SZ);   // V transposed

  scan_kernel<<<1, 512, 0, stream>>>(na, offs, B, total, out);
  cvt_kernel<<<64, 256, 0, stream>>>(wm23, WM0);
  cvt_kernel<<<64, 256, 0, stream>>>(wm32, WM1);

  dim3 blk(256);
  dim3 gP(total / 128, 2);   // [total,256] gemms
  dim3 gV(2, total / 128);   // transposed-V gemm: M=256, N=total
  dim3 gA(B);                // fused attention+outproj: 1 block/graph
  dim3 blkA(512);

  // branch 2d -> 3d
  gemm_kernel<<<gP, blk, 0, stream>>>(rep2d, wq23, bq23, BQ, 256, 0);
  gemm_kernel<<<gP, blk, 0, stream>>>(rep3d, wk23, bk23, BK, 256, 0);
  gemm_kernel<<<gV, blk, 0, stream>>>(wv23, rep3d, bv23, BV, total, 1);
  attn_out_kernel<<<gA, blkA, 0, stream>>>(BQ, BK, BV, WM0, bm23, out, offs, total);

  // branch 3d -> 2d
  gemm_kernel<<<gP, blk, 0, stream>>>(rep3d, wq32, bq32, BQ, 256, 0);
  gemm_kernel<<<gP, blk, 0, stream>>>(rep2d, wk32, bk32, BK, 256, 0);
  gemm_kernel<<<gV, blk, 0, stream>>>(wv32, rep2d, bv32, BV, total, 1);
  attn_out_kernel<<<gA, blkA, 0, stream>>>(BQ, BK, BV, WM1, bm32,
                                           out + (size_t)total * 256, offs, total);
}

// Round 11
// 238.715 us; speedup vs baseline: 1.5479x; 1.5479x over previous
//
#include <hip/hip_runtime.h>
#include <hip/hip_bf16.h>
#include <cstdint>

// ---------------------------------------------------------------------------
// InteractionMHA, fp32 I/O, bf16-MFMA compute.
//   proj6:    all 6 projection GEMMs, one dispatch (grid z=6, 1920 blocks)
//   attn2:    both branches' attention, one dispatch (grid y=2, 1024 blocks)
//   gemm_out2: both branches' gelu(X@Wm^T+bm), one dispatch (grid z=2)
// Round-11: fusion reverted (r10: compiler spilled at VGPR=68, 157us).
// Components are the proven r7/r8 parts; the only change is dispatch merging
// for machine fill (each solo dispatch filled <=1.25 blocks/CU of ~5 capacity).
// Needs 6-buffer ws (126MB, proven present r8/r9); 3-buffer fallback kept.
// ---------------------------------------------------------------------------

typedef short s16x8 __attribute__((ext_vector_type(8)));
typedef float f32x4 __attribute__((ext_vector_type(4)));

__device__ __forceinline__ s16x8 cvt8(const float* p) {
  float4 a0 = *(const float4*)p, a1 = *(const float4*)(p + 4);
  union { s16x8 v; __bf16 e[8]; } u;
  u.e[0] = (__bf16)a0.x; u.e[1] = (__bf16)a0.y; u.e[2] = (__bf16)a0.z; u.e[3] = (__bf16)a0.w;
  u.e[4] = (__bf16)a1.x; u.e[5] = (__bf16)a1.y; u.e[6] = (__bf16)a1.z; u.e[7] = (__bf16)a1.w;
  return u.v;
}
__device__ __forceinline__ float fast_gelu(float x) {
  float ax = fabsf(x);
  float t = 1.0f / (1.0f + 0.3275911f * (ax * 0.70710678f));
  float y = t * (0.254829592f + t * (-0.284496736f + t * (1.421413741f +
            t * (-1.453152027f + t * 1.061405429f))));
  float er = 1.0f - y * __expf(-0.5f * ax * ax);
  er = (x < 0.f) ? -er : er;
  return 0.5f * x * (1.0f + er);
}

__global__ void sentinel_kernel(float* out, float v) {
  if (threadIdx.x == 0 && blockIdx.x == 0) out[0] = v;
}

// ---------- parallel offsets scan (B <= 512), dtype self-validating --------
__global__ __launch_bounds__(512) void scan_kernel(
    const int* __restrict__ na, int* __restrict__ offs,
    int B, int total, float* out)
{
  __shared__ int s32[512];
  __shared__ int s64[512];
  const int t = threadIdx.x;
  int v32 = 0, v64 = 0;
  if (t < B) {
    v32 = na[t];
    v64 = (int)((const long long*)na)[t];
  }
  s32[t] = v32; s64[t] = v64;
  __syncthreads();
  for (int o = 1; o < 512; o <<= 1) {
    int a = (t >= o) ? s32[t - o] : 0;
    int b = (t >= o) ? s64[t - o] : 0;
    __syncthreads();
    s32[t] += a; s64[t] += b;
    __syncthreads();
  }
  int tot32 = s32[B - 1], tot64 = s64[B - 1];
  bool ok32 = (tot32 == total), ok64 = (tot64 == total);
  if (t < B) offs[t] = ok32 ? (s32[t] - v32) : ok64 ? (s64[t] - v64) : 0;
  if (t == 0) {
    offs[B] = ok32 ? tot32 : ok64 ? tot64 : 0;
    if (!ok32 && !ok64) out[0] = 31337.0f;
  }
}

// ---------- merged 6-way projection GEMM (r7 inner loop, proven) -----------
struct Proj6Args {
  const float* A[6]; const float* W[6]; const float* bias[6];
  unsigned long long C[6];               // __bf16* as u64 (POD for by-value)
};
__global__ __launch_bounds__(256) void proj6_kernel(Proj6Args args, int total)
{
  __shared__ __bf16 At[128 * 32];
  __shared__ __bf16 Bt[128 * 32];
  const int z = blockIdx.z;
  const bool vcase = (z == 2 || z == 5);   // V projections: swapped operands
  const float* A  = args.A[z];
  const float* Bw = args.W[z];
  const float* bs = args.bias[z];
  __bf16* C = (__bf16*)args.C[z];
  const int N = vcase ? total : 256;
  const int by = vcase ? blockIdx.y : blockIdx.x;   // M-tile
  const int bx = vcase ? blockIdx.x : blockIdx.y;   // N-tile
  if (vcase && blockIdx.x >= (unsigned)(total / 128)) return;
  if (!vcase && blockIdx.y >= 2) return;

  const int t = threadIdx.x;
  const int lane = t & 63, w = t >> 6;
  const int wr = w >> 1, wc = w & 1;
  const int l15 = lane & 15, l4 = lane >> 4;

  f32x4 acc[4][4];
  for (int m = 0; m < 4; ++m)
    for (int nn = 0; nn < 4; ++nn) acc[m][nn] = (f32x4){0.f, 0.f, 0.f, 0.f};

  for (int kk = 0; kk < 256; kk += 32) {
    for (int j = 0; j < 2; ++j) {
      int c = t + j * 256;
      int row = c >> 2, off0 = (c & 3) * 8;
      *(s16x8*)(&At[row * 32 + off0]) = cvt8(A + (size_t)(by * 128 + row) * 256 + kk + off0);
      *(s16x8*)(&Bt[row * 32 + off0]) = cvt8(Bw + (size_t)(bx * 128 + row) * 256 + kk + off0);
    }
    __syncthreads();
    s16x8 af[4], bfr[4];
    for (int m = 0; m < 4; ++m)
      af[m] = *(const s16x8*)(&At[(wr * 64 + m * 16 + l15) * 32 + l4 * 8]);
    for (int nn = 0; nn < 4; ++nn)
      bfr[nn] = *(const s16x8*)(&Bt[(wc * 64 + nn * 16 + l15) * 32 + l4 * 8]);
    for (int m = 0; m < 4; ++m)
      for (int nn = 0; nn < 4; ++nn)
        acc[m][nn] = __builtin_amdgcn_mfma_f32_16x16x32_bf16(af[m], bfr[nn], acc[m][nn], 0, 0, 0);
    __syncthreads();
  }

  for (int m = 0; m < 4; ++m) {
    int row0 = by * 128 + wr * 64 + m * 16 + l4 * 4;
    for (int nn = 0; nn < 4; ++nn) {
      int col = bx * 128 + wc * 64 + nn * 16 + l15;
      float bc = vcase ? 0.f : bs[col];
      for (int r = 0; r < 4; ++r) {
        int row = row0 + r;
        float v = acc[m][nn][r] + (vcase ? bs[row] : bc);
        C[(size_t)row * N + col] = (__bf16)v;
      }
    }
  }
}

// ---------- merged 2-way attention (r4 inner loop, proven) -----------------
struct Attn2Args {
  const __bf16* Q[2]; const __bf16* K[2]; const __bf16* V[2];
  unsigned long long X[2];
};
#define KSTR 264
#define PSTR 136
__global__ __launch_bounds__(512, 2) void attn2_kernel(
    Attn2Args args, const int* __restrict__ offs, int total)
{
  __shared__ __bf16 smem[128 * KSTR];
  __bf16 (*Klds)[KSTR] = (__bf16(*)[KSTR])smem;
  __bf16 (*Plds)[PSTR] = (__bf16(*)[PSTR])smem;

  const int br = blockIdx.y;
  const __bf16* Q  = args.Q[br];
  const __bf16* Km = args.K[br];
  const __bf16* Vt = args.V[br];
  __bf16* X = (__bf16*)args.X[br];

  const int g = blockIdx.x;
  const int off = offs[g];
  const int n = offs[g + 1] - off;
  const int t = threadIdx.x, lane = t & 63, w = t >> 6;
  const int l15 = lane & 15, l4 = lane >> 4;
  const bool qact = (w * 16) < n;

  uint4 kst[8];
  #pragma unroll
  for (int j = 0; j < 8; ++j) {
    int row = j * 16 + (t >> 5);
    kst[j] = *(const uint4*)((const char*)(Km + (size_t)(off + row) * 256) + (t & 31) * 16);
  }
  s16x8 qf[8];
  if (qact) {
    int qr = w * 16 + l15; if (qr >= n) qr = n - 1;
    const __bf16* qp = Q + (size_t)(off + qr) * 256 + l4 * 8;
    #pragma unroll
    for (int kk = 0; kk < 8; ++kk) qf[kk] = *(const s16x8*)(qp + kk * 32);
  }
  #pragma unroll
  for (int j = 0; j < 8; ++j) {
    int row = j * 16 + (t >> 5);
    *(uint4*)((char*)&Klds[row][0] + (t & 31) * 16) = kst[j];
  }
  __syncthreads();

  f32x4 sacc[8];
  #pragma unroll
  for (int i = 0; i < 8; ++i) sacc[i] = (f32x4){0.f, 0.f, 0.f, 0.f};
  if (qact) {
    #pragma unroll
    for (int kt = 0; kt < 8; ++kt) {
      if (kt * 16 < n) {
        const __bf16* kp = &Klds[kt * 16 + l15][l4 * 8];
        #pragma unroll
        for (int kk = 0; kk < 8; ++kk) {
          s16x8 kf = *(const s16x8*)(kp + kk * 32);
          sacc[kt] = __builtin_amdgcn_mfma_f32_16x16x32_bf16(qf[kk], kf, sacc[kt], 0, 0, 0);
        }
      }
    }
  }
  __syncthreads();

  if (qact) {
    #pragma unroll
    for (int r = 0; r < 4; ++r) {
      float sv[8];
      float m = -1e30f;
      #pragma unroll
      for (int kt = 0; kt < 8; ++kt) {
        int key = kt * 16 + l15;
        float v = (key < n) ? sacc[kt][r] * 0.0625f : -1e30f;
        sv[kt] = v; m = fmaxf(m, v);
      }
      for (int o = 1; o < 16; o <<= 1) m = fmaxf(m, __shfl_xor(m, o));
      float p[8], sum = 0.f;
      #pragma unroll
      for (int kt = 0; kt < 8; ++kt) { p[kt] = __expf(sv[kt] - m); sum += p[kt]; }
      for (int o = 1; o < 16; o <<= 1) sum += __shfl_xor(sum, o);
      float inv = 1.f / sum;
      int q = w * 16 + l4 * 4 + r;
      #pragma unroll
      for (int kt = 0; kt < 8; ++kt)
        Plds[q][kt * 16 + l15] = (__bf16)(p[kt] * inv);
    }
  }
  __syncthreads();

  const int dbase = w * 32;
  f32x4 xacc[2][8];
  #pragma unroll
  for (int dt = 0; dt < 2; ++dt)
    #pragma unroll
    for (int qm = 0; qm < 8; ++qm) xacc[dt][qm] = (f32x4){0.f, 0.f, 0.f, 0.f};

  #pragma unroll
  for (int dt = 0; dt < 2; ++dt) {
    int d = dbase + dt * 16 + l15;
    s16x8 vf[4];
    #pragma unroll
    for (int ks = 0; ks < 4; ++ks) {
      int kc = off + ks * 32 + l4 * 8;
      if (kc > total - 8) kc = total - 8;
      vf[ks] = *(const s16x8*)(Vt + (size_t)d * total + kc);
    }
    #pragma unroll
    for (int qm = 0; qm < 8; ++qm) {
      #pragma unroll
      for (int ks = 0; ks < 4; ++ks) {
        if (ks * 32 < n) {
          s16x8 pa = *(const s16x8*)(&Plds[qm * 16 + l15][ks * 32 + l4 * 8]);
          xacc[dt][qm] = __builtin_amdgcn_mfma_f32_16x16x32_bf16(pa, vf[ks], xacc[dt][qm], 0, 0, 0);
        }
      }
    }
  }

  #pragma unroll
  for (int dt = 0; dt < 2; ++dt)
    #pragma unroll
    for (int qm = 0; qm < 8; ++qm)
      #pragma unroll
      for (int r = 0; r < 4; ++r) {
        int q = qm * 16 + l4 * 4 + r;
        if (q < n)
          X[(size_t)(off + q) * 256 + dbase + dt * 16 + l15] = (__bf16)xacc[dt][qm][r];
      }
}

// ---------- merged 2-way out-proj (r7 inner loop, proven) ------------------
struct Out2Args {
  const __bf16* A[2]; const float* W[2]; const float* bias[2];
  unsigned long long C[2];
};
__global__ __launch_bounds__(256) void gemm_out2(Out2Args args)
{
  __shared__ __bf16 At[64 * 32];
  __shared__ __bf16 Bt[128 * 32];
  const int z = blockIdx.z;
  const __bf16* A  = args.A[z];
  const float* Bw  = args.W[z];
  const float* bias = args.bias[z];
  float* C = (float*)args.C[z];

  const int t = threadIdx.x;
  const int lane = t & 63, w = t >> 6;
  const int wr = w >> 1, wc = w & 1;
  const int l15 = lane & 15, l4 = lane >> 4;
  const int by = blockIdx.x, bx = blockIdx.y;

  f32x4 acc[2][4];
  for (int m = 0; m < 2; ++m)
    for (int nn = 0; nn < 4; ++nn) acc[m][nn] = (f32x4){0.f, 0.f, 0.f, 0.f};

  for (int kk = 0; kk < 256; kk += 32) {
    {
      int row = t >> 2, off0 = (t & 3) * 8;
      *(s16x8*)(&At[row * 32 + off0]) =
          *(const s16x8*)(A + (size_t)(by * 64 + row) * 256 + kk + off0);
    }
    for (int j = 0; j < 2; ++j) {
      int c = t + j * 256;
      int row = c >> 2, off0 = (c & 3) * 8;
      *(s16x8*)(&Bt[row * 32 + off0]) = cvt8(Bw + (size_t)(bx * 128 + row) * 256 + kk + off0);
    }
    __syncthreads();
    s16x8 af[2], bfr[4];
    for (int m = 0; m < 2; ++m)
      af[m] = *(const s16x8*)(&At[(wr * 32 + m * 16 + l15) * 32 + l4 * 8]);
    for (int nn = 0; nn < 4; ++nn)
      bfr[nn] = *(const s16x8*)(&Bt[(wc * 64 + nn * 16 + l15) * 32 + l4 * 8]);
    for (int m = 0; m < 2; ++m)
      for (int nn = 0; nn < 4; ++nn)
        acc[m][nn] = __builtin_amdgcn_mfma_f32_16x16x32_bf16(af[m], bfr[nn], acc[m][nn], 0, 0, 0);
    __syncthreads();
  }

  for (int m = 0; m < 2; ++m) {
    int row0 = by * 64 + wr * 32 + m * 16 + l4 * 4;
    for (int nn = 0; nn < 4; ++nn) {
      int col = bx * 128 + wc * 64 + nn * 16 + l15;
      float bc = bias[col];
      for (int r = 0; r < 4; ++r) {
        int row = row0 + r;
        C[(size_t)row * 256 + col] = fast_gelu(acc[m][nn][r] + bc);
      }
    }
  }
}

// ---------- fallback single-buffer-set kernels (r7, proven) ----------------
__global__ __launch_bounds__(256) void gemm_kernel(
    const float* __restrict__ A, const float* __restrict__ Bw,
    const float* __restrict__ bias, __bf16* __restrict__ C,
    int N, int biasRow)
{
  __shared__ __bf16 At[128 * 32];
  __shared__ __bf16 Bt[128 * 32];
  const int t = threadIdx.x;
  const int lane = t & 63, w = t >> 6;
  const int wr = w >> 1, wc = w & 1;
  const int l15 = lane & 15, l4 = lane >> 4;
  const int by = blockIdx.x, bx = blockIdx.y;

  f32x4 acc[4][4];
  for (int m = 0; m < 4; ++m)
    for (int nn = 0; nn < 4; ++nn) acc[m][nn] = (f32x4){0.f, 0.f, 0.f, 0.f};

  for (int kk = 0; kk < 256; kk += 32) {
    for (int j = 0; j < 2; ++j) {
      int c = t + j * 256;
      int row = c >> 2, off0 = (c & 3) * 8;
      *(s16x8*)(&At[row * 32 + off0]) = cvt8(A + (size_t)(by * 128 + row) * 256 + kk + off0);
      *(s16x8*)(&Bt[row * 32 + off0]) = cvt8(Bw + (size_t)(bx * 128 + row) * 256 + kk + off0);
    }
    __syncthreads();
    s16x8 af[4], bfr[4];
    for (int m = 0; m < 4; ++m)
      af[m] = *(const s16x8*)(&At[(wr * 64 + m * 16 + l15) * 32 + l4 * 8]);
    for (int nn = 0; nn < 4; ++nn)
      bfr[nn] = *(const s16x8*)(&Bt[(wc * 64 + nn * 16 + l15) * 32 + l4 * 8]);
    for (int m = 0; m < 4; ++m)
      for (int nn = 0; nn < 4; ++nn)
        acc[m][nn] = __builtin_amdgcn_mfma_f32_16x16x32_bf16(af[m], bfr[nn], acc[m][nn], 0, 0, 0);
    __syncthreads();
  }

  for (int m = 0; m < 4; ++m) {
    int row0 = by * 128 + wr * 64 + m * 16 + l4 * 4;
    for (int nn = 0; nn < 4; ++nn) {
      int col = bx * 128 + wc * 64 + nn * 16 + l15;
      float bc = biasRow ? 0.f : bias[col];
      for (int r = 0; r < 4; ++r) {
        int row = row0 + r;
        float v = acc[m][nn][r] + (biasRow ? bias[row] : bc);
        C[(size_t)row * N + col] = (__bf16)v;
      }
    }
  }
}

// ---------------------------------------------------------------------------
extern "C" void kernel_launch(void* const* d_in, const int* in_sizes, int n_in,
                              void* d_out, int out_size, void* d_ws, size_t ws_size,
                              hipStream_t stream) {
  const float* rep2d = (const float*)d_in[0];
  const float* rep3d = (const float*)d_in[1];
  const int*   na    = (const int*)d_in[2];
  const float* wq23 = (const float*)d_in[3];  const float* bq23 = (const float*)d_in[4];
  const float* wk23 = (const float*)d_in[5];  const float* bk23 = (const float*)d_in[6];
  const float* wv23 = (const float*)d_in[7];  const float* bv23 = (const float*)d_in[8];
  const float* wq32 = (const float*)d_in[9];  const float* bq32 = (const float*)d_in[10];
  const float* wk32 = (const float*)d_in[11]; const float* bk32 = (const float*)d_in[12];
  const float* wv32 = (const float*)d_in[13]; const float* bv32 = (const float*)d_in[14];
  const float* wm23 = (const float*)d_in[15]; const float* bm23 = (const float*)d_in[16];
  const float* wm32 = (const float*)d_in[17]; const float* bm32 = (const float*)d_in[18];

  const int B = in_sizes[2];
  const int total = in_sizes[0] / 256;           // 40960
  float* out = (float*)d_out;

  char* ws = (char*)d_ws;
  const size_t SZ = (size_t)total * 256 * sizeof(__bf16);  // 20.97 MB
  const size_t need6 = 8192 + 6 * SZ;                      // 125.9 MB (proven r8/r9)
  const size_t need3 = 8192 + 3 * SZ;                      // 62.9 MB
  int* offs = (int*)ws;

  dim3 blk(256);
  dim3 blkA(512);

  if (ws_size >= need6) {
    __bf16* BQ1 = (__bf16*)(ws + 8192);
    __bf16* BK1 = (__bf16*)(ws + 8192 + SZ);
    __bf16* BV1 = (__bf16*)(ws + 8192 + 2 * SZ);
    __bf16* BQ2 = (__bf16*)(ws + 8192 + 3 * SZ);
    __bf16* BK2 = (__bf16*)(ws + 8192 + 4 * SZ);
    __bf16* BV2 = (__bf16*)(ws + 8192 + 5 * SZ);

    scan_kernel<<<1, 512, 0, stream>>>(na, offs, B, total, out);

    Proj6Args pa;
    // z: 0 Q23(rep2d), 1 K23(rep3d), 2 V23(rep3d, swapped), 3 Q32(rep3d),
    //    4 K32(rep2d), 5 V32(rep2d, swapped)
    pa.A[0] = rep2d; pa.W[0] = wq23; pa.bias[0] = bq23; pa.C[0] = (unsigned long long)BQ1;
    pa.A[1] = rep3d; pa.W[1] = wk23; pa.bias[1] = bk23; pa.C[1] = (unsigned long long)BK1;
    pa.A[2] = wv23;  pa.W[2] = rep3d; pa.bias[2] = bv23; pa.C[2] = (unsigned long long)BV1;
    pa.A[3] = rep3d; pa.W[3] = wq32; pa.bias[3] = bq32; pa.C[3] = (unsigned long long)BQ2;
    pa.A[4] = rep2d; pa.W[4] = wk32; pa.bias[4] = bk32; pa.C[4] = (unsigned long long)BK2;
    pa.A[5] = wv32;  pa.W[5] = rep2d; pa.bias[5] = bv32; pa.C[5] = (unsigned long long)BV2;
    proj6_kernel<<<dim3(total / 128, 2, 6), blk, 0, stream>>>(pa, total);

    Attn2Args aa;
    aa.Q[0] = BQ1; aa.K[0] = BK1; aa.V[0] = BV1; aa.X[0] = (unsigned long long)BQ1;
    aa.Q[1] = BQ2; aa.K[1] = BK2; aa.V[1] = BV2; aa.X[1] = (unsigned long long)BQ2;
    attn2_kernel<<<dim3(B, 2), blkA, 0, stream>>>(aa, offs, total);

    Out2Args oa;
    oa.A[0] = BQ1; oa.W[0] = wm23; oa.bias[0] = bm23; oa.C[0] = (unsigned long long)out;
    oa.A[1] = BQ2; oa.W[1] = wm32; oa.bias[1] = bm32;
    oa.C[1] = (unsigned long long)(out + (size_t)total * 256);
    gemm_out2<<<dim3(total / 64, 2, 2), blk, 0, stream>>>(oa);
  } else if (ws_size >= need3) {
    __bf16* BQ = (__bf16*)(ws + 8192);
    __bf16* BK = (__bf16*)(ws + 8192 + SZ);
    __bf16* BV = (__bf16*)(ws + 8192 + 2 * SZ);
    dim3 gP(total / 128, 2);
    dim3 gV(2, total / 128);
    dim3 gA(B);

    scan_kernel<<<1, 512, 0, stream>>>(na, offs, B, total, out);
    for (int br = 0; br < 2; ++br) {
      const float* rq = br ? rep3d : rep2d;
      const float* rk = br ? rep2d : rep3d;
      const float* wq = br ? wq32 : wq23;  const float* bq = br ? bq32 : bq23;
      const float* wk = br ? wk32 : wk23;  const float* bk = br ? bk32 : bk23;
      const float* wv = br ? wv32 : wv23;  const float* bv = br ? bv32 : bv23;
      const float* wm = br ? wm32 : wm23;  const float* bm = br ? bm32 : bm23;
      float* o = out + (size_t)br * total * 256;

      gemm_kernel<<<gP, blk, 0, stream>>>(rq, wq, bq, BQ, 256, 0);
      gemm_kernel<<<gP, blk, 0, stream>>>(rk, wk, bk, BK, 256, 0);
      gemm_kernel<<<gV, blk, 0, stream>>>(wv, rk, bv, BV, total, 1);
      Attn2Args aa;
      aa.Q[0] = BQ; aa.K[0] = BK; aa.V[0] = BV; aa.X[0] = (unsigned long long)BQ;
      aa.Q[1] = BQ; aa.K[1] = BK; aa.V[1] = BV; aa.X[1] = (unsigned long long)BQ;
      attn2_kernel<<<dim3(B, 1), blkA, 0, stream>>>(aa, offs, total);
      Out2Args oa;
      oa.A[0] = BQ; oa.W[0] = wm; oa.bias[0] = bm; oa.C[0] = (unsigned long long)o;
      oa.A[1] = BQ; oa.W[1] = wm; oa.bias[1] = bm; oa.C[1] = (unsigned long long)o;
      gemm_out2<<<dim3(total / 64, 2, 1), blk, 0, stream>>>(oa);
    }
  } else {
    sentinel_kernel<<<1, 64, 0, stream>>>(out, 54321.0f);
  }
}

// Round 12
// 211.172 us; speedup vs baseline: 1.7498x; 1.1304x over previous
//
#include <hip/hip_runtime.h>
#include <hip/hip_bf16.h>
#include <cstdint>

// ---------------------------------------------------------------------------
// InteractionMHA, fp32 I/O, bf16-MFMA compute.
//   6 separate projection dispatches (r7 structure, 5.7 TB/s measured):
//     Q/K: gemm_kernel; V: vgemm_kernel (LDS-transpose epilogue -> contiguous
//     256B Vt row-segment stores, replacing the 2B scatter that made V ~25us)
//   attn2:     both branches' attention, one dispatch (r11: merged = big win)
//   gemm_out2: both branches' gelu(X@Wm^T+bm), one dispatch
// Round-12: r11 showed merged proj6 = 166us vs ~94us separate (L2 stream
// thrash) while merged attn2+out2 = ~69us vs 130us separate. Keep each
// component in its measured-best form.
// ---------------------------------------------------------------------------

typedef short s16x8 __attribute__((ext_vector_type(8)));
typedef float f32x4 __attribute__((ext_vector_type(4)));

__device__ __forceinline__ s16x8 cvt8(const float* p) {
  float4 a0 = *(const float4*)p, a1 = *(const float4*)(p + 4);
  union { s16x8 v; __bf16 e[8]; } u;
  u.e[0] = (__bf16)a0.x; u.e[1] = (__bf16)a0.y; u.e[2] = (__bf16)a0.z; u.e[3] = (__bf16)a0.w;
  u.e[4] = (__bf16)a1.x; u.e[5] = (__bf16)a1.y; u.e[6] = (__bf16)a1.z; u.e[7] = (__bf16)a1.w;
  return u.v;
}
__device__ __forceinline__ float fast_gelu(float x) {
  float ax = fabsf(x);
  float t = 1.0f / (1.0f + 0.3275911f * (ax * 0.70710678f));
  float y = t * (0.254829592f + t * (-0.284496736f + t * (1.421413741f +
            t * (-1.453152027f + t * 1.061405429f))));
  float er = 1.0f - y * __expf(-0.5f * ax * ax);
  er = (x < 0.f) ? -er : er;
  return 0.5f * x * (1.0f + er);
}

__global__ void sentinel_kernel(float* out, float v) {
  if (threadIdx.x == 0 && blockIdx.x == 0) out[0] = v;
}

// ---------- parallel offsets scan (B <= 512), dtype self-validating --------
__global__ __launch_bounds__(512) void scan_kernel(
    const int* __restrict__ na, int* __restrict__ offs,
    int B, int total, float* out)
{
  __shared__ int s32[512];
  __shared__ int s64[512];
  const int t = threadIdx.x;
  int v32 = 0, v64 = 0;
  if (t < B) {
    v32 = na[t];
    v64 = (int)((const long long*)na)[t];
  }
  s32[t] = v32; s64[t] = v64;
  __syncthreads();
  for (int o = 1; o < 512; o <<= 1) {
    int a = (t >= o) ? s32[t - o] : 0;
    int b = (t >= o) ? s64[t - o] : 0;
    __syncthreads();
    s32[t] += a; s64[t] += b;
    __syncthreads();
  }
  int tot32 = s32[B - 1], tot64 = s64[B - 1];
  bool ok32 = (tot32 == total), ok64 = (tot64 == total);
  if (t < B) offs[t] = ok32 ? (s32[t] - v32) : ok64 ? (s64[t] - v64) : 0;
  if (t == 0) {
    offs[B] = ok32 ? tot32 : ok64 ? tot64 : 0;
    if (!ok32 && !ok64) out[0] = 31337.0f;
  }
}

// ---------- Q/K projection GEMM (r7 proven): C = A@Bw^T + bias, bf16 -------
__global__ __launch_bounds__(256) void gemm_kernel(
    const float* __restrict__ A, const float* __restrict__ Bw,
    const float* __restrict__ bias, __bf16* __restrict__ C, int N)
{
  __shared__ __bf16 At[128 * 32];
  __shared__ __bf16 Bt[128 * 32];
  const int t = threadIdx.x;
  const int lane = t & 63, w = t >> 6;
  const int wr = w >> 1, wc = w & 1;
  const int l15 = lane & 15, l4 = lane >> 4;
  const int by = blockIdx.x, bx = blockIdx.y;

  f32x4 acc[4][4];
  for (int m = 0; m < 4; ++m)
    for (int nn = 0; nn < 4; ++nn) acc[m][nn] = (f32x4){0.f, 0.f, 0.f, 0.f};

  for (int kk = 0; kk < 256; kk += 32) {
    for (int j = 0; j < 2; ++j) {
      int c = t + j * 256;
      int row = c >> 2, off0 = (c & 3) * 8;
      *(s16x8*)(&At[row * 32 + off0]) = cvt8(A + (size_t)(by * 128 + row) * 256 + kk + off0);
      *(s16x8*)(&Bt[row * 32 + off0]) = cvt8(Bw + (size_t)(bx * 128 + row) * 256 + kk + off0);
    }
    __syncthreads();
    s16x8 af[4], bfr[4];
    for (int m = 0; m < 4; ++m)
      af[m] = *(const s16x8*)(&At[(wr * 64 + m * 16 + l15) * 32 + l4 * 8]);
    for (int nn = 0; nn < 4; ++nn)
      bfr[nn] = *(const s16x8*)(&Bt[(wc * 64 + nn * 16 + l15) * 32 + l4 * 8]);
    for (int m = 0; m < 4; ++m)
      for (int nn = 0; nn < 4; ++nn)
        acc[m][nn] = __builtin_amdgcn_mfma_f32_16x16x32_bf16(af[m], bfr[nn], acc[m][nn], 0, 0, 0);
    __syncthreads();
  }

  for (int m = 0; m < 4; ++m) {
    int row0 = by * 128 + wr * 64 + m * 16 + l4 * 4;
    for (int nn = 0; nn < 4; ++nn) {
      int col = bx * 128 + wc * 64 + nn * 16 + l15;
      float bc = bias[col];
      for (int r = 0; r < 4; ++r) {
        int row = row0 + r;
        C[(size_t)row * N + col] = (__bf16)(acc[m][nn][r] + bc);
      }
    }
  }
}

// ---------- V projection: Vt[256][total] = Wv@rep^T + bv (row bias) --------
// Same MFMA core; epilogue transposes the 128x128 tile through LDS so global
// stores are 16B chunks in 256B-contiguous row segments (no partial lines).
#define CTP 136
__global__ __launch_bounds__(256) void vgemm_kernel(
    const float* __restrict__ A, const float* __restrict__ Bw,
    const float* __restrict__ bias, __bf16* __restrict__ Vt, int total)
{
  __shared__ __bf16 At[128 * 32];
  __shared__ __bf16 Bt[128 * 32];
  __shared__ __bf16 Ct[128 * CTP];       // 34.8 KB, pitch 272B (16B-aligned)
  const int t = threadIdx.x;
  const int lane = t & 63, w = t >> 6;
  const int wr = w >> 1, wc = w & 1;
  const int l15 = lane & 15, l4 = lane >> 4;
  const int by = blockIdx.x, bx = blockIdx.y;   // by: d-tile (0/1), bx: atom-tile

  f32x4 acc[4][4];
  for (int m = 0; m < 4; ++m)
    for (int nn = 0; nn < 4; ++nn) acc[m][nn] = (f32x4){0.f, 0.f, 0.f, 0.f};

  for (int kk = 0; kk < 256; kk += 32) {
    for (int j = 0; j < 2; ++j) {
      int c = t + j * 256;
      int row = c >> 2, off0 = (c & 3) * 8;
      *(s16x8*)(&At[row * 32 + off0]) = cvt8(A + (size_t)(by * 128 + row) * 256 + kk + off0);
      *(s16x8*)(&Bt[row * 32 + off0]) = cvt8(Bw + (size_t)(bx * 128 + row) * 256 + kk + off0);
    }
    __syncthreads();
    s16x8 af[4], bfr[4];
    for (int m = 0; m < 4; ++m)
      af[m] = *(const s16x8*)(&At[(wr * 64 + m * 16 + l15) * 32 + l4 * 8]);
    for (int nn = 0; nn < 4; ++nn)
      bfr[nn] = *(const s16x8*)(&Bt[(wc * 64 + nn * 16 + l15) * 32 + l4 * 8]);
    for (int m = 0; m < 4; ++m)
      for (int nn = 0; nn < 4; ++nn)
        acc[m][nn] = __builtin_amdgcn_mfma_f32_16x16x32_bf16(af[m], bfr[nn], acc[m][nn], 0, 0, 0);
    __syncthreads();
  }

  // epilogue: +row-bias, stage tile in LDS [d_local][atom_local]
  for (int m = 0; m < 4; ++m) {
    int rl0 = wr * 64 + m * 16 + l4 * 4;
    for (int nn = 0; nn < 4; ++nn) {
      int cl = wc * 64 + nn * 16 + l15;
      for (int r = 0; r < 4; ++r) {
        int rl = rl0 + r;
        Ct[rl * CTP + cl] = (__bf16)(acc[m][nn][r] + bias[by * 128 + rl]);
      }
    }
  }
  __syncthreads();

  // store: 2048 16B chunks (128 rows x 16 segs), 8 per thread; each row gets
  // a contiguous 256B segment of Vt -> full cachelines, no RMW
  for (int i = 0; i < 8; ++i) {
    int c = t + i * 256;
    int row = c >> 4, seg = c & 15;
    *(uint4*)(Vt + (size_t)(by * 128 + row) * total + bx * 128 + seg * 8) =
        *(const uint4*)(&Ct[row * CTP + seg * 8]);
  }
}

// ---------- merged 2-way attention (r4 inner loop, r11 merge win) ----------
struct Attn2Args {
  const __bf16* Q[2]; const __bf16* K[2]; const __bf16* V[2];
  unsigned long long X[2];
};
#define KSTR 264
#define PSTR 136
__global__ __launch_bounds__(512, 2) void attn2_kernel(
    Attn2Args args, const int* __restrict__ offs, int total)
{
  __shared__ __bf16 smem[128 * KSTR];
  __bf16 (*Klds)[KSTR] = (__bf16(*)[KSTR])smem;
  __bf16 (*Plds)[PSTR] = (__bf16(*)[PSTR])smem;

  const int br = blockIdx.y;
  const __bf16* Q  = args.Q[br];
  const __bf16* Km = args.K[br];
  const __bf16* Vt = args.V[br];
  __bf16* X = (__bf16*)args.X[br];

  const int g = blockIdx.x;
  const int off = offs[g];
  const int n = offs[g + 1] - off;
  const int t = threadIdx.x, lane = t & 63, w = t >> 6;
  const int l15 = lane & 15, l4 = lane >> 4;
  const bool qact = (w * 16) < n;

  uint4 kst[8];
  #pragma unroll
  for (int j = 0; j < 8; ++j) {
    int row = j * 16 + (t >> 5);
    kst[j] = *(const uint4*)((const char*)(Km + (size_t)(off + row) * 256) + (t & 31) * 16);
  }
  s16x8 qf[8];
  if (qact) {
    int qr = w * 16 + l15; if (qr >= n) qr = n - 1;
    const __bf16* qp = Q + (size_t)(off + qr) * 256 + l4 * 8;
    #pragma unroll
    for (int kk = 0; kk < 8; ++kk) qf[kk] = *(const s16x8*)(qp + kk * 32);
  }
  #pragma unroll
  for (int j = 0; j < 8; ++j) {
    int row = j * 16 + (t >> 5);
    *(uint4*)((char*)&Klds[row][0] + (t & 31) * 16) = kst[j];
  }
  __syncthreads();

  f32x4 sacc[8];
  #pragma unroll
  for (int i = 0; i < 8; ++i) sacc[i] = (f32x4){0.f, 0.f, 0.f, 0.f};
  if (qact) {
    #pragma unroll
    for (int kt = 0; kt < 8; ++kt) {
      if (kt * 16 < n) {
        const __bf16* kp = &Klds[kt * 16 + l15][l4 * 8];
        #pragma unroll
        for (int kk = 0; kk < 8; ++kk) {
          s16x8 kf = *(const s16x8*)(kp + kk * 32);
          sacc[kt] = __builtin_amdgcn_mfma_f32_16x16x32_bf16(qf[kk], kf, sacc[kt], 0, 0, 0);
        }
      }
    }
  }
  __syncthreads();

  if (qact) {
    #pragma unroll
    for (int r = 0; r < 4; ++r) {
      float sv[8];
      float m = -1e30f;
      #pragma unroll
      for (int kt = 0; kt < 8; ++kt) {
        int key = kt * 16 + l15;
        float v = (key < n) ? sacc[kt][r] * 0.0625f : -1e30f;
        sv[kt] = v; m = fmaxf(m, v);
      }
      for (int o = 1; o < 16; o <<= 1) m = fmaxf(m, __shfl_xor(m, o));
      float p[8], sum = 0.f;
      #pragma unroll
      for (int kt = 0; kt < 8; ++kt) { p[kt] = __expf(sv[kt] - m); sum += p[kt]; }
      for (int o = 1; o < 16; o <<= 1) sum += __shfl_xor(sum, o);
      float inv = 1.f / sum;
      int q = w * 16 + l4 * 4 + r;
      #pragma unroll
      for (int kt = 0; kt < 8; ++kt)
        Plds[q][kt * 16 + l15] = (__bf16)(p[kt] * inv);
    }
  }
  __syncthreads();

  const int dbase = w * 32;
  f32x4 xacc[2][8];
  #pragma unroll
  for (int dt = 0; dt < 2; ++dt)
    #pragma unroll
    for (int qm = 0; qm < 8; ++qm) xacc[dt][qm] = (f32x4){0.f, 0.f, 0.f, 0.f};

  #pragma unroll
  for (int dt = 0; dt < 2; ++dt) {
    int d = dbase + dt * 16 + l15;
    s16x8 vf[4];
    #pragma unroll
    for (int ks = 0; ks < 4; ++ks) {
      int kc = off + ks * 32 + l4 * 8;
      if (kc > total - 8) kc = total - 8;
      vf[ks] = *(const s16x8*)(Vt + (size_t)d * total + kc);
    }
    #pragma unroll
    for (int qm = 0; qm < 8; ++qm) {
      #pragma unroll
      for (int ks = 0; ks < 4; ++ks) {
        if (ks * 32 < n) {
          s16x8 pa = *(const s16x8*)(&Plds[qm * 16 + l15][ks * 32 + l4 * 8]);
          xacc[dt][qm] = __builtin_amdgcn_mfma_f32_16x16x32_bf16(pa, vf[ks], xacc[dt][qm], 0, 0, 0);
        }
      }
    }
  }

  #pragma unroll
  for (int dt = 0; dt < 2; ++dt)
    #pragma unroll
    for (int qm = 0; qm < 8; ++qm)
      #pragma unroll
      for (int r = 0; r < 4; ++r) {
        int q = qm * 16 + l4 * 4 + r;
        if (q < n)
          X[(size_t)(off + q) * 256 + dbase + dt * 16 + l15] = (__bf16)xacc[dt][qm][r];
      }
}

// ---------- merged 2-way out-proj (r7 inner loop, r11 merge win) -----------
struct Out2Args {
  const __bf16* A[2]; const float* W[2]; const float* bias[2];
  unsigned long long C[2];
};
__global__ __launch_bounds__(256) void gemm_out2(Out2Args args)
{
  __shared__ __bf16 At[64 * 32];
  __shared__ __bf16 Bt[128 * 32];
  const int z = blockIdx.z;
  const __bf16* A  = args.A[z];
  const float* Bw  = args.W[z];
  const float* bias = args.bias[z];
  float* C = (float*)args.C[z];

  const int t = threadIdx.x;
  const int lane = t & 63, w = t >> 6;
  const int wr = w >> 1, wc = w & 1;
  const int l15 = lane & 15, l4 = lane >> 4;
  const int by = blockIdx.x, bx = blockIdx.y;

  f32x4 acc[2][4];
  for (int m = 0; m < 2; ++m)
    for (int nn = 0; nn < 4; ++nn) acc[m][nn] = (f32x4){0.f, 0.f, 0.f, 0.f};

  for (int kk = 0; kk < 256; kk += 32) {
    {
      int row = t >> 2, off0 = (t & 3) * 8;
      *(s16x8*)(&At[row * 32 + off0]) =
          *(const s16x8*)(A + (size_t)(by * 64 + row) * 256 + kk + off0);
    }
    for (int j = 0; j < 2; ++j) {
      int c = t + j * 256;
      int row = c >> 2, off0 = (c & 3) * 8;
      *(s16x8*)(&Bt[row * 32 + off0]) = cvt8(Bw + (size_t)(bx * 128 + row) * 256 + kk + off0);
    }
    __syncthreads();
    s16x8 af[2], bfr[4];
    for (int m = 0; m < 2; ++m)
      af[m] = *(const s16x8*)(&At[(wr * 32 + m * 16 + l15) * 32 + l4 * 8]);
    for (int nn = 0; nn < 4; ++nn)
      bfr[nn] = *(const s16x8*)(&Bt[(wc * 64 + nn * 16 + l15) * 32 + l4 * 8]);
    for (int m = 0; m < 2; ++m)
      for (int nn = 0; nn < 4; ++nn)
        acc[m][nn] = __builtin_amdgcn_mfma_f32_16x16x32_bf16(af[m], bfr[nn], acc[m][nn], 0, 0, 0);
    __syncthreads();
  }

  for (int m = 0; m < 2; ++m) {
    int row0 = by * 64 + wr * 32 + m * 16 + l4 * 4;
    for (int nn = 0; nn < 4; ++nn) {
      int col = bx * 128 + wc * 64 + nn * 16 + l15;
      float bc = bias[col];
      for (int r = 0; r < 4; ++r) {
        int row = row0 + r;
        C[(size_t)row * 256 + col] = fast_gelu(acc[m][nn][r] + bc);
      }
    }
  }
}

// ---------------------------------------------------------------------------
extern "C" void kernel_launch(void* const* d_in, const int* in_sizes, int n_in,
                              void* d_out, int out_size, void* d_ws, size_t ws_size,
                              hipStream_t stream) {
  const float* rep2d = (const float*)d_in[0];
  const float* rep3d = (const float*)d_in[1];
  const int*   na    = (const int*)d_in[2];
  const float* wq23 = (const float*)d_in[3];  const float* bq23 = (const float*)d_in[4];
  const float* wk23 = (const float*)d_in[5];  const float* bk23 = (const float*)d_in[6];
  const float* wv23 = (const float*)d_in[7];  const float* bv23 = (const float*)d_in[8];
  const float* wq32 = (const float*)d_in[9];  const float* bq32 = (const float*)d_in[10];
  const float* wk32 = (const float*)d_in[11]; const float* bk32 = (const float*)d_in[12];
  const float* wv32 = (const float*)d_in[13]; const float* bv32 = (const float*)d_in[14];
  const float* wm23 = (const float*)d_in[15]; const float* bm23 = (const float*)d_in[16];
  const float* wm32 = (const float*)d_in[17]; const float* bm32 = (const float*)d_in[18];

  const int B = in_sizes[2];
  const int total = in_sizes[0] / 256;           // 40960
  float* out = (float*)d_out;

  char* ws = (char*)d_ws;
  const size_t SZ = (size_t)total * 256 * sizeof(__bf16);  // 20.97 MB
  const size_t need6 = 8192 + 6 * SZ;                      // 125.9 MB (proven)
  const size_t need3 = 8192 + 3 * SZ;                      // 62.9 MB
  int* offs = (int*)ws;

  dim3 blk(256);
  dim3 blkA(512);
  dim3 gP(total / 128, 2);   // Q/K gemms
  dim3 gV(2, total / 128);   // V gemms (d-tiles, atom-tiles)

  if (ws_size >= need6) {
    __bf16* BQ1 = (__bf16*)(ws + 8192);
    __bf16* BK1 = (__bf16*)(ws + 8192 + SZ);
    __bf16* BV1 = (__bf16*)(ws + 8192 + 2 * SZ);
    __bf16* BQ2 = (__bf16*)(ws + 8192 + 3 * SZ);
    __bf16* BK2 = (__bf16*)(ws + 8192 + 4 * SZ);
    __bf16* BV2 = (__bf16*)(ws + 8192 + 5 * SZ);

    scan_kernel<<<1, 512, 0, stream>>>(na, offs, B, total, out);
    gemm_kernel<<<gP, blk, 0, stream>>>(rep2d, wq23, bq23, BQ1, 256);
    gemm_kernel<<<gP, blk, 0, stream>>>(rep3d, wk23, bk23, BK1, 256);
    vgemm_kernel<<<gV, blk, 0, stream>>>(wv23, rep3d, bv23, BV1, total);
    gemm_kernel<<<gP, blk, 0, stream>>>(rep3d, wq32, bq32, BQ2, 256);
    gemm_kernel<<<gP, blk, 0, stream>>>(rep2d, wk32, bk32, BK2, 256);
    vgemm_kernel<<<gV, blk, 0, stream>>>(wv32, rep2d, bv32, BV2, total);

    Attn2Args aa;
    aa.Q[0] = BQ1; aa.K[0] = BK1; aa.V[0] = BV1; aa.X[0] = (unsigned long long)BQ1;
    aa.Q[1] = BQ2; aa.K[1] = BK2; aa.V[1] = BV2; aa.X[1] = (unsigned long long)BQ2;
    attn2_kernel<<<dim3(B, 2), blkA, 0, stream>>>(aa, offs, total);

    Out2Args oa;
    oa.A[0] = BQ1; oa.W[0] = wm23; oa.bias[0] = bm23; oa.C[0] = (unsigned long long)out;
    oa.A[1] = BQ2; oa.W[1] = wm32; oa.bias[1] = bm32;
    oa.C[1] = (unsigned long long)(out + (size_t)total * 256);
    gemm_out2<<<dim3(total / 64, 2, 2), blk, 0, stream>>>(oa);
  } else if (ws_size >= need3) {
    __bf16* BQ = (__bf16*)(ws + 8192);
    __bf16* BK = (__bf16*)(ws + 8192 + SZ);
    __bf16* BV = (__bf16*)(ws + 8192 + 2 * SZ);

    scan_kernel<<<1, 512, 0, stream>>>(na, offs, B, total, out);
    for (int br = 0; br < 2; ++br) {
      const float* rq = br ? rep3d : rep2d;
      const float* rk = br ? rep2d : rep3d;
      const float* wq = br ? wq32 : wq23;  const float* bq = br ? bq32 : bq23;
      const float* wk = br ? wk32 : wk23;  const float* bk = br ? bk32 : bk23;
      const float* wv = br ? wv32 : wv23;  const float* bv = br ? bv32 : bv23;
      const float* wm = br ? wm32 : wm23;  const float* bm = br ? bm32 : bm23;
      float* o = out + (size_t)br * total * 256;

      gemm_kernel<<<gP, blk, 0, stream>>>(rq, wq, bq, BQ, 256);
      gemm_kernel<<<gP, blk, 0, stream>>>(rk, wk, bk, BK, 256);
      vgemm_kernel<<<gV, blk, 0, stream>>>(wv, rk, bv, BV, total);
      Attn2Args aa;
      aa.Q[0] = BQ; aa.K[0] = BK; aa.V[0] = BV; aa.X[0] = (unsigned long long)BQ;
      aa.Q[1] = BQ; aa.K[1] = BK; aa.V[1] = BV; aa.X[1] = (unsigned long long)BQ;
      attn2_kernel<<<dim3(B, 1), blkA, 0, stream>>>(aa, offs, total);
      Out2Args oa;
      oa.A[0] = BQ; oa.W[0] = wm; oa.bias[0] = bm; oa.C[0] = (unsigned long long)o;
      oa.A[1] = BQ; oa.W[1] = wm; oa.bias[1] = bm; oa.C[1] = (unsigned long long)o;
      gemm_out2<<<dim3(total / 64, 2, 1), blk, 0, stream>>>(oa);
    }
  } else {
    sentinel_kernel<<<1, 64, 0, stream>>>(out, 54321.0f);
  }
}